// Round 1
// baseline (1133.989 us; speedup 1.0000x reference)
//
#include <hip/hip_runtime.h>

// ---------------------------------------------------------------------------
// SageCox: 4-layer GraphSAGE (mean aggr) on N=100000 nodes, E=640000 edges.
// Per layer: out = mean_neighbors(x)[dst] @ Wl + bl + x @ Wr
// Restructured: p = x@Wl; acc = x@Wr + bl; acc[dst] += p[src] * inv_deg[dst].
// acc becomes next layer's input directly.
// ---------------------------------------------------------------------------

__global__ void deg_kernel(const int* __restrict__ edst, float* __restrict__ deg, int E) {
    int i = blockIdx.x * blockDim.x + threadIdx.x;
    if (i < E) atomicAdd(&deg[edst[i]], 1.0f);
}

__global__ void invdeg_kernel(float* __restrict__ deg, int N) {
    int i = blockIdx.x * blockDim.x + threadIdx.x;
    if (i < N) deg[i] = 1.0f / fmaxf(deg[i], 1.0f);
}

// Each block stages R rows of x in LDS, then computes p = x@Wl and
// acc = x@Wr + bl for those rows. Thread->output mapping has the output
// column fastest so W reads are coalesced across lanes at each k.
template <int DIN, int DOUT, int R>
__global__ void proj_kernel(const float* __restrict__ x,
                            const float* __restrict__ Wl,
                            const float* __restrict__ bl,
                            const float* __restrict__ Wr,
                            float* __restrict__ p,
                            float* __restrict__ acc,
                            int N) {
    __shared__ float xs[R][DIN];
    const int row0 = blockIdx.x * R;

    for (int i = threadIdx.x; i < R * DIN; i += blockDim.x) {
        const int r = i / DIN;
        const int k = i - r * DIN;
        const int row = row0 + r;
        xs[r][k] = (row < N) ? x[(size_t)row * DIN + k] : 0.0f;
    }
    __syncthreads();

    const int TOT = R * DOUT * 2;
    for (int o = threadIdx.x; o < TOT; o += blockDim.x) {
        const int c = o % DOUT;
        const int t = o / DOUT;
        const int r = t % R;
        const int which = t / R;  // 0 -> Wl/p, 1 -> Wr/acc(+bias)
        const int row = row0 + r;
        if (row >= N) continue;
        const float* __restrict__ W = which ? Wr : Wl;
        float s = which ? bl[c] : 0.0f;
#pragma unroll 8
        for (int k = 0; k < DIN; ++k)
            s = fmaf(xs[r][k], W[k * DOUT + c], s);
        if (which) acc[(size_t)row * DOUT + c] = s;
        else       p[(size_t)row * DOUT + c] = s;
    }
}

// Edge-parallel scatter: acc[dst] += p[src] * inv_deg[dst], column-fastest
// so each edge's row read / atomic writes are coalesced across lanes.
template <int DOUT>
__global__ void scatter_kernel(const int* __restrict__ esrc,
                               const int* __restrict__ edst,
                               const float* __restrict__ p,
                               const float* __restrict__ invdeg,
                               float* __restrict__ acc,
                               int E) {
    const int total = E * DOUT;
    const int stride = gridDim.x * blockDim.x;
    for (int idx = blockIdx.x * blockDim.x + threadIdx.x; idx < total; idx += stride) {
        const int e = idx / DOUT;
        const int c = idx - e * DOUT;
        const int s = esrc[e];
        const int d = edst[e];
        atomicAdd(&acc[(size_t)d * DOUT + c], p[(size_t)s * DOUT + c] * invdeg[d]);
    }
}

extern "C" void kernel_launch(void* const* d_in, const int* in_sizes, int n_in,
                              void* d_out, int out_size, void* d_ws, size_t ws_size,
                              hipStream_t stream) {
    const float* x   = (const float*)d_in[0];
    const int*   ei  = (const int*)d_in[1];
    const int N = in_sizes[0] / 128;
    const int E = in_sizes[1] / 2;
    const int* esrc = ei;        // edge_index[0]
    const int* edst = ei + E;    // edge_index[1]

    const float* Wl[4] = {(const float*)d_in[2], (const float*)d_in[5],
                          (const float*)d_in[8], (const float*)d_in[11]};
    const float* bl[4] = {(const float*)d_in[3], (const float*)d_in[6],
                          (const float*)d_in[9], (const float*)d_in[12]};
    const float* Wr[4] = {(const float*)d_in[4], (const float*)d_in[7],
                          (const float*)d_in[10], (const float*)d_in[13]};

    float* ws   = (float*)d_ws;
    float* deg  = ws;                         // N
    float* pbuf = ws + N;                     // N * 85 (max dout)
    float* bufA = pbuf + (size_t)N * 85;      // N * 85
    float* bufB = bufA + (size_t)N * 85;      // N * 85

    // Degree (same for all layers).
    hipMemsetAsync(deg, 0, (size_t)N * sizeof(float), stream);
    deg_kernel<<<(E + 255) / 256, 256, 0, stream>>>(edst, deg, E);
    invdeg_kernel<<<(N + 255) / 256, 256, 0, stream>>>(deg, N);

    // Layer 0: 128 -> 85   (x from d_in, acc -> bufA)
    proj_kernel<128, 85, 8><<<(N + 7) / 8, 256, 0, stream>>>(
        x, Wl[0], bl[0], Wr[0], pbuf, bufA, N);
    scatter_kernel<85><<<2048, 256, 0, stream>>>(esrc, edst, pbuf, deg, bufA, E);

    // Layer 1: 85 -> 56    (bufA -> bufB)
    proj_kernel<85, 56, 8><<<(N + 7) / 8, 256, 0, stream>>>(
        bufA, Wl[1], bl[1], Wr[1], pbuf, bufB, N);
    scatter_kernel<56><<<2048, 256, 0, stream>>>(esrc, edst, pbuf, deg, bufB, E);

    // Layer 2: 56 -> 28    (bufB -> bufA)
    proj_kernel<56, 28, 16><<<(N + 15) / 16, 256, 0, stream>>>(
        bufB, Wl[2], bl[2], Wr[2], pbuf, bufA, N);
    scatter_kernel<28><<<2048, 256, 0, stream>>>(esrc, edst, pbuf, deg, bufA, E);

    // Layer 3: 28 -> 1     (bufA -> d_out)
    proj_kernel<28, 1, 128><<<(N + 127) / 128, 256, 0, stream>>>(
        bufA, Wl[3], bl[3], Wr[3], pbuf, (float*)d_out, N);
    scatter_kernel<1><<<1024, 256, 0, stream>>>(esrc, edst, pbuf, deg, (float*)d_out, E);
}

// Round 2
// 577.874 us; speedup vs baseline: 1.9623x; 1.9623x over previous
//
#include <hip/hip_runtime.h>

// ---------------------------------------------------------------------------
// SageCox: 4-layer GraphSAGE (mean aggr), N=100000 nodes, E=640000 edges.
// Per layer: out = mean_neigh(x) @ Wl + bl + x @ Wr
// Restructured: p = x@Wl ; acc = x@Wr + bl ; acc[d] += invdeg[d]*sum p[src].
// Aggregation via CSR gather (no float atomics). Proj = register-tiled GEMM
// over concatenated, padded weights Wcat = [Wl | Wr | 0-pad].
// ---------------------------------------------------------------------------

#define NNODES 100000
#define NEDGES 640000

// ---- CSR build ------------------------------------------------------------

__global__ void hist_kernel(const int* __restrict__ edst, int* __restrict__ deg, int E) {
    int i = blockIdx.x * blockDim.x + threadIdx.x;
    if (i < E) atomicAdd(&deg[edst[i]], 1);
}

// per-block sums of deg
__global__ void scanA_kernel(const int* __restrict__ deg, int* __restrict__ bsum, int N) {
    __shared__ int s[256];
    int i = blockIdx.x * 256 + threadIdx.x;
    s[threadIdx.x] = (i < N) ? deg[i] : 0;
    __syncthreads();
    for (int off = 128; off > 0; off >>= 1) {
        if (threadIdx.x < off) s[threadIdx.x] += s[threadIdx.x + off];
        __syncthreads();
    }
    if (threadIdx.x == 0) bsum[blockIdx.x] = s[0];
}

// exclusive scan of block sums (single block, 512 threads, nb <= 512)
__global__ void scanB_kernel(const int* __restrict__ bsum, int* __restrict__ bpre, int nb) {
    __shared__ int s[512];
    int t = threadIdx.x;
    int v = (t < nb) ? bsum[t] : 0;
    s[t] = v;
    __syncthreads();
    for (int off = 1; off < 512; off <<= 1) {
        int add = (t >= off) ? s[t - off] : 0;
        __syncthreads();
        s[t] += add;
        __syncthreads();
    }
    if (t < nb) bpre[t] = s[t] - v;  // exclusive
}

// per-element exclusive scan + block offset -> rowptr, cursor
__global__ void scanC_kernel(const int* __restrict__ deg, const int* __restrict__ bpre,
                             int* __restrict__ rowptr, int* __restrict__ cursor, int N, int E) {
    __shared__ int s[256];
    int t = threadIdx.x;
    int i = blockIdx.x * 256 + t;
    int v = (i < N) ? deg[i] : 0;
    s[t] = v;
    __syncthreads();
    for (int off = 1; off < 256; off <<= 1) {
        int add = (t >= off) ? s[t - off] : 0;
        __syncthreads();
        s[t] += add;
        __syncthreads();
    }
    if (i < N) {
        int excl = bpre[blockIdx.x] + s[t] - v;
        rowptr[i] = excl;
        cursor[i] = excl;
        if (i == N - 1) rowptr[N] = E;
    }
}

__global__ void fill_kernel(const int* __restrict__ esrc, const int* __restrict__ edst,
                            int* __restrict__ cursor, int* __restrict__ csr, int E) {
    int i = blockIdx.x * blockDim.x + threadIdx.x;
    if (i < E) {
        int pos = atomicAdd(&cursor[edst[i]], 1);
        csr[pos] = esrc[i];
    }
}

// ---- weight pack: Wcat[k][c] = c<DOUT ? Wl : (DOUTP<=c<DOUTP+DOUT ? Wr : 0)

__global__ void pack_kernel(const float* __restrict__ Wl, const float* __restrict__ Wr,
                            float* __restrict__ Wcat, int DIN, int DOUT, int DOUTP, int CWALL) {
    int idx = blockIdx.x * blockDim.x + threadIdx.x;
    int tot = DIN * CWALL;
    if (idx >= tot) return;
    int k = idx / CWALL, c = idx - k * CWALL;
    float v = 0.0f;
    if (c < DOUT) v = Wl[k * DOUT + c];
    else if (c >= DOUTP && c < DOUTP + DOUT) v = Wr[k * DOUT + (c - DOUTP)];
    Wcat[idx] = v;
}

// ---- projection: p = x@Wl, out = x@Wr + bl, register-tiled 4x4 ------------

template <int DIN, int DOUT, int DOUTP, int CWALL>
__global__ void __launch_bounds__(256)
proj_kernel(const float* __restrict__ x, const float* __restrict__ Wcat,
            const float* __restrict__ bl, float* __restrict__ p,
            float* __restrict__ out, int N) {
    __shared__ float xs[64][DIN + 1];
    const int row0 = blockIdx.x * 64;

    for (int idx = threadIdx.x; idx < 64 * DIN; idx += 256) {
        int r = idx / DIN, k = idx - r * DIN;
        int row = row0 + r;
        xs[r][k] = (row < N) ? x[(size_t)row * DIN + k] : 0.0f;
    }
    __syncthreads();

    const int cq = threadIdx.x & 15;        // col-quad within tile
    const int rq = threadIdx.x >> 4;        // row-quad (0..15)
    const int c0 = blockIdx.y * 64 + cq * 4;
    const int r0 = rq * 4;

    float acc[4][4] = {};
    const float* __restrict__ wp = Wcat + c0;

#pragma unroll 4
    for (int k = 0; k < DIN; ++k) {
        const float4 w = *(const float4*)(wp + (size_t)k * CWALL);
        float xv[4];
#pragma unroll
        for (int j = 0; j < 4; ++j) xv[j] = xs[r0 + j][k];
#pragma unroll
        for (int j = 0; j < 4; ++j) {
            acc[j][0] = fmaf(xv[j], w.x, acc[j][0]);
            acc[j][1] = fmaf(xv[j], w.y, acc[j][1]);
            acc[j][2] = fmaf(xv[j], w.z, acc[j][2]);
            acc[j][3] = fmaf(xv[j], w.w, acc[j][3]);
        }
    }

#pragma unroll
    for (int j = 0; j < 4; ++j) {
        const int row = row0 + r0 + j;
        if (row >= N) continue;
#pragma unroll
        for (int i = 0; i < 4; ++i) {
            const int c = c0 + i;
            if (c < DOUT) {
                p[(size_t)row * DOUT + c] = acc[j][i];
            } else if (c >= DOUTP && c < DOUTP + DOUT) {
                const int co = c - DOUTP;
                out[(size_t)row * DOUT + co] = acc[j][i] + bl[co];
            }
        }
    }
}

// ---- gather aggregation: out[d] += invdeg * sum_{s in N(d)} p[s] ----------

template <int DOUT>
__global__ void __launch_bounds__(256)
gather_kernel(const int* __restrict__ rowptr, const int* __restrict__ csr,
              const float* __restrict__ p, float* __restrict__ out, int N) {
    const int node = (blockIdx.x * 256 + threadIdx.x) >> 6;
    const int lane = threadIdx.x & 63;
    if (node >= N) return;
    const int beg = rowptr[node];
    const int end = rowptr[node + 1];
    const float inv = 1.0f / (float)max(end - beg, 1);
    float a0 = 0.0f, a1 = 0.0f;
    for (int j = beg; j < end; ++j) {
        const int s = csr[j];
        const float* __restrict__ pr = p + (size_t)s * DOUT;
        if (lane < DOUT) a0 += pr[lane];
        if (DOUT > 64 && lane + 64 < DOUT) a1 += pr[lane + 64];
    }
    if (lane < DOUT) out[(size_t)node * DOUT + lane] += inv * a0;
    if (DOUT > 64 && lane + 64 < DOUT) out[(size_t)node * DOUT + lane + 64] += inv * a1;
}

__global__ void gather1_kernel(const int* __restrict__ rowptr, const int* __restrict__ csr,
                               const float* __restrict__ p, float* __restrict__ out, int N) {
    const int node = blockIdx.x * blockDim.x + threadIdx.x;
    if (node >= N) return;
    const int beg = rowptr[node];
    const int end = rowptr[node + 1];
    const float inv = 1.0f / (float)max(end - beg, 1);
    float a = 0.0f;
    for (int j = beg; j < end; ++j) a += p[csr[j]];
    out[node] += inv * a;
}

// ---- layer 3 (28 -> 1) GEMV ----------------------------------------------

__global__ void __launch_bounds__(256)
gemv3_kernel(const float* __restrict__ x, const float* __restrict__ Wl,
             const float* __restrict__ bl, const float* __restrict__ Wr,
             float* __restrict__ p, float* __restrict__ out, int N) {
    __shared__ float xs[256 * 28];
    const int row0 = blockIdx.x * 256;
    for (int idx = threadIdx.x; idx < 256 * 28; idx += 256) {
        int r = row0 + idx / 28;
        xs[idx] = (r < N) ? x[(size_t)row0 * 28 + idx] : 0.0f;
    }
    __syncthreads();
    const int row = row0 + threadIdx.x;
    if (row >= N) return;
    float sl = 0.0f, sr = 0.0f;
#pragma unroll
    for (int k = 0; k < 28; ++k) {
        const float xv = xs[threadIdx.x * 28 + k];
        sl = fmaf(xv, Wl[k], sl);
        sr = fmaf(xv, Wr[k], sr);
    }
    p[row] = sl;
    out[row] = sr + bl[0];
}

// ---------------------------------------------------------------------------

extern "C" void kernel_launch(void* const* d_in, const int* in_sizes, int n_in,
                              void* d_out, int out_size, void* d_ws, size_t ws_size,
                              hipStream_t stream) {
    const float* x  = (const float*)d_in[0];
    const int*   ei = (const int*)d_in[1];
    const int N = NNODES;
    const int E = NEDGES;
    const int* esrc = ei;
    const int* edst = ei + E;

    const float* Wl[4] = {(const float*)d_in[2], (const float*)d_in[5],
                          (const float*)d_in[8], (const float*)d_in[11]};
    const float* bl[4] = {(const float*)d_in[3], (const float*)d_in[6],
                          (const float*)d_in[9], (const float*)d_in[12]};
    const float* Wr[4] = {(const float*)d_in[4], (const float*)d_in[7],
                          (const float*)d_in[10], (const float*)d_in[13]};

    // workspace layout (floats), 16B-aligned chunks
    float* ws = (float*)d_ws;
    size_t off = 0;
    auto alloc = [&](size_t n) { float* r = ws + off; off += (n + 3) & ~(size_t)3; return r; };
    float* Wc0  = alloc(128 * 192);
    float* Wc1  = alloc(85 * 128);
    float* Wc2  = alloc(56 * 64);
    float* pbuf = alloc((size_t)N * 85);
    float* bufA = alloc((size_t)N * 85);
    float* bufB = alloc((size_t)N * 56);
    int* degi   = (int*)alloc(N);
    int* rowptr = (int*)alloc(N + 1);
    int* cursor = (int*)alloc(N);
    int* csr    = (int*)alloc(E);
    int* bsum   = (int*)alloc(512);
    int* bpre   = (int*)alloc(512);

    const int nb = (N + 255) / 256;  // 391

    // CSR build
    hipMemsetAsync(degi, 0, (size_t)N * sizeof(int), stream);
    hist_kernel<<<(E + 255) / 256, 256, 0, stream>>>(edst, degi, E);
    scanA_kernel<<<nb, 256, 0, stream>>>(degi, bsum, N);
    scanB_kernel<<<1, 512, 0, stream>>>(bsum, bpre, nb);
    scanC_kernel<<<nb, 256, 0, stream>>>(degi, bpre, rowptr, cursor, N, E);
    fill_kernel<<<(E + 255) / 256, 256, 0, stream>>>(esrc, edst, cursor, csr, E);

    // weight packs
    pack_kernel<<<(128 * 192 + 255) / 256, 256, 0, stream>>>(Wl[0], Wr[0], Wc0, 128, 85, 88, 192);
    pack_kernel<<<(85 * 128 + 255) / 256, 256, 0, stream>>>(Wl[1], Wr[1], Wc1, 85, 56, 56, 128);
    pack_kernel<<<(56 * 64 + 255) / 256, 256, 0, stream>>>(Wl[2], Wr[2], Wc2, 56, 28, 28, 64);

    const int rowTiles = (N + 63) / 64;  // 1563

    // Layer 0: 128 -> 85
    proj_kernel<128, 85, 88, 192><<<dim3(rowTiles, 3), 256, 0, stream>>>(
        x, Wc0, bl[0], pbuf, bufA, N);
    gather_kernel<85><<<(N + 3) / 4, 256, 0, stream>>>(rowptr, csr, pbuf, bufA, N);

    // Layer 1: 85 -> 56
    proj_kernel<85, 56, 56, 128><<<dim3(rowTiles, 2), 256, 0, stream>>>(
        bufA, Wc1, bl[1], pbuf, bufB, N);
    gather_kernel<56><<<(N + 3) / 4, 256, 0, stream>>>(rowptr, csr, pbuf, bufB, N);

    // Layer 2: 56 -> 28  (acc reuses bufA with stride 28)
    proj_kernel<56, 28, 28, 64><<<dim3(rowTiles, 1), 256, 0, stream>>>(
        bufB, Wc2, bl[2], pbuf, bufA, N);
    gather_kernel<28><<<(N + 3) / 4, 256, 0, stream>>>(rowptr, csr, pbuf, bufA, N);

    // Layer 3: 28 -> 1
    gemv3_kernel<<<(N + 255) / 256, 256, 0, stream>>>(
        bufA, Wl[3], bl[3], Wr[3], pbuf, (float*)d_out, N);
    gather1_kernel<<<(N + 255) / 256, 256, 0, stream>>>(
        rowptr, csr, pbuf, (float*)d_out, N);
}